// Round 2
// baseline (895.205 us; speedup 1.0000x reference)
//
#include <hip/hip_runtime.h>
#include <hip/hip_bf16.h>

#define BB 8
#define NN 4096
#define CC 256
#define TARGET 1024
#define NHI 614
#define NUNI 410
#define NREM 3482   // NN - NHI
#define RPAD 3584   // padded per-batch stride for rem arrays

// ---------------------------------------------------------------------------
// K1: curvature = unbiased variance of 16-NN (sqrt) distances, one wave/row.
// ---------------------------------------------------------------------------
__global__ __launch_bounds__(1024) void k_curv(const float* __restrict__ xyz,
                                               float* __restrict__ curv) {
    __shared__ float lx[NN], ly[NN], lz[NN];
    const int b    = blockIdx.x >> 8;           // 256 blocks per batch
    const int row0 = (blockIdx.x & 255) << 4;   // 16 rows per block
    const int tid  = threadIdx.x;

    for (int i = tid; i < NN; i += 1024) {
        const float* p = xyz + ((size_t)b * NN + i) * 3;
        lx[i] = p[0]; ly[i] = p[1]; lz[i] = p[2];
    }
    __syncthreads();

    const int lane = tid & 63;
    const int row  = row0 + (tid >> 6);
    const float px = lx[row], py = ly[row], pz = lz[row];

    // per-lane sorted (ascending) top-17 of packed (d2_bits<<32 | idx)
    unsigned long long lst[17];
#pragma unroll
    for (int s = 0; s < 17; ++s) lst[s] = ~0ULL;

    for (int k = 0; k < 64; ++k) {
        const int j = lane + (k << 6);
        float dx = __fsub_rn(lx[j], px);
        float dy = __fsub_rn(ly[j], py);
        float dz = __fsub_rn(lz[j], pz);
        float d2 = __fadd_rn(__fadd_rn(__fmul_rn(dx, dx), __fmul_rn(dy, dy)),
                             __fmul_rn(dz, dz));
        unsigned long long key =
            ((unsigned long long)__float_as_uint(d2) << 32) | (unsigned)j;
        if (key < lst[16]) {
            lst[16] = key;
#pragma unroll
            for (int s = 16; s > 0; --s) {   // bubble the new element up
                if (lst[s] < lst[s - 1]) {
                    unsigned long long t = lst[s];
                    lst[s] = lst[s - 1];
                    lst[s - 1] = t;
                }
            }
        }
    }

    // wave-wide pop-merge: 17 rounds of min-butterfly; round 0 pops self (d2=0)
    float dv[17];
#pragma unroll
    for (int r = 0; r < 17; ++r) {
        unsigned long long mine = lst[0];
        unsigned long long h = mine;
#pragma unroll
        for (int o = 32; o > 0; o >>= 1) {
            unsigned long long other = __shfl_xor(h, o, 64);
            h = other < h ? other : h;
        }
        if (mine == h) {          // unique owner pops (keys are unique by idx)
#pragma unroll
            for (int s = 0; s < 16; ++s) lst[s] = lst[s + 1];
            lst[16] = ~0ULL;
        }
        dv[r] = __fsqrt_rn(__uint_as_float((unsigned)(h >> 32)));
    }

    // mean & unbiased variance over dv[1..16], sequential ascending order
    float sum = 0.0f;
#pragma unroll
    for (int r = 1; r < 17; ++r) sum = __fadd_rn(sum, dv[r]);
    float mean = __fmul_rn(sum, 0.0625f);   // /16 (power of two, exact either way)
    float vs = 0.0f;
#pragma unroll
    for (int r = 1; r < 17; ++r) {
        float c = __fsub_rn(dv[r], mean);
        vs = __fadd_rn(vs, __fmul_rn(c, c));
    }
    float var = __fdiv_rn(vs, 15.0f);       // ddof=1

    if (lane == 0) curv[b * NN + row] = var;
}

// ---------------------------------------------------------------------------
// K2: per-batch bitonic sort (desc curv, asc idx) -> hi[614]; mask + prefix
//     scan -> rem indices (ascending) + gathered SoA coords.
// ---------------------------------------------------------------------------
__global__ __launch_bounds__(1024) void k_sort(const float* __restrict__ curv,
                                               const float* __restrict__ xyz,
                                               int* __restrict__ sel,
                                               int* __restrict__ ridx,
                                               float* __restrict__ rx,
                                               float* __restrict__ ry,
                                               float* __restrict__ rz) {
    __shared__ unsigned long long keys[NN];
    __shared__ unsigned int valid[NN];
    __shared__ int wsum[16];
    __shared__ int woff[16];
    const int b = blockIdx.x;
    const int tid = threadIdx.x;
    const int lane = tid & 63;
    const int w = tid >> 6;

    for (int i = tid; i < NN; i += 1024) {
        float c = curv[b * NN + i];
        keys[i] = ((unsigned long long)(~__float_as_uint(c)) << 32) | (unsigned)i;
        valid[i] = 1u;
    }
    __syncthreads();

    for (int k = 2; k <= NN; k <<= 1) {
        for (int j = k >> 1; j > 0; j >>= 1) {
            for (int i = tid; i < NN; i += 1024) {
                int ixj = i ^ j;
                if (ixj > i) {
                    unsigned long long a = keys[i], c = keys[ixj];
                    bool up = ((i & k) == 0);
                    if ((a > c) == up) { keys[i] = c; keys[ixj] = a; }
                }
            }
            __syncthreads();
        }
    }

    if (tid < NHI) {
        int hi = (int)(unsigned)(keys[tid] & 0xFFFFFFFFu);
        sel[b * TARGET + tid] = hi;
        valid[hi] = 0u;
    }
    __syncthreads();

    // block exclusive scan over 4096 validity flags, 4 per thread (index order)
    const int i0 = tid * 4;
    int v0 = (int)valid[i0], v1 = (int)valid[i0 + 1];
    int v2 = (int)valid[i0 + 2], v3 = (int)valid[i0 + 3];
    int msum = v0 + v1 + v2 + v3;
    int scan = msum;
#pragma unroll
    for (int o = 1; o < 64; o <<= 1) {
        int n = __shfl_up(scan, o, 64);
        if (lane >= o) scan += n;
    }
    if (lane == 63) wsum[w] = scan;
    __syncthreads();
    if (tid == 0) {
        int acc = 0;
        for (int q = 0; q < 16; ++q) { woff[q] = acc; acc += wsum[q]; }
    }
    __syncthreads();
    int pos = woff[w] + (scan - msum);

    const float* xb = xyz + (size_t)b * NN * 3;
    const int rb = b * RPAD;
    if (v0) { ridx[rb + pos] = i0;     rx[rb + pos] = xb[i0 * 3];       ry[rb + pos] = xb[i0 * 3 + 1];       rz[rb + pos] = xb[i0 * 3 + 2];       ++pos; }
    if (v1) { ridx[rb + pos] = i0 + 1; rx[rb + pos] = xb[(i0 + 1) * 3]; ry[rb + pos] = xb[(i0 + 1) * 3 + 1]; rz[rb + pos] = xb[(i0 + 1) * 3 + 2]; ++pos; }
    if (v2) { ridx[rb + pos] = i0 + 2; rx[rb + pos] = xb[(i0 + 2) * 3]; ry[rb + pos] = xb[(i0 + 2) * 3 + 1]; rz[rb + pos] = xb[(i0 + 2) * 3 + 2]; ++pos; }
    if (v3) { ridx[rb + pos] = i0 + 3; rx[rb + pos] = xb[(i0 + 3) * 3]; ry[rb + pos] = xb[(i0 + 3) * 3 + 1]; rz[rb + pos] = xb[(i0 + 3) * 3 + 2]; ++pos; }
}

// ---------------------------------------------------------------------------
// K3: farthest point sampling, one block (256 thr) per batch, 410 serial iters
// ---------------------------------------------------------------------------
__global__ __launch_bounds__(256) void k_fps(const int* __restrict__ ridx,
                                             const float* __restrict__ rx,
                                             const float* __restrict__ ry,
                                             const float* __restrict__ rz,
                                             int* __restrict__ sel) {
    __shared__ float sx[NREM], sy[NREM], sz[NREM];
    __shared__ int sid[NREM];
    __shared__ unsigned long long wkey[4];
    const int b = blockIdx.x, tid = threadIdx.x;
    const int w = tid >> 6;
    const int rb = b * RPAD;

    float px[14], py[14], pz[14], dist[14];
#pragma unroll
    for (int s = 0; s < 14; ++s) {
        int g = tid + 256 * s;
        bool ok = g < NREM;
        int gi = ok ? g : 0;
        float x = rx[rb + gi], y = ry[rb + gi], z = rz[rb + gi];
        px[s] = x; py[s] = y; pz[s] = z;
        dist[s] = ok ? __builtin_huge_valf() : -1.0f;
        if (ok) { sx[g] = x; sy[g] = y; sz[g] = z; sid[g] = ridx[rb + g]; }
    }
    __syncthreads();

    int far = 0;
    for (int it = 0; it < NUNI; ++it) {
        if (tid == 0) sel[b * TARGET + NHI + it] = sid[far];  // emit carry (pre-update)
        const float fx = sx[far], fy = sy[far], fz = sz[far];
        unsigned long long best = 0ULL;
#pragma unroll
        for (int s = 0; s < 14; ++s) {
            int g = tid + 256 * s;
            if (g < NREM) {
                float dx = __fsub_rn(px[s], fx);
                float dy = __fsub_rn(py[s], fy);
                float dz = __fsub_rn(pz[s], fz);
                float d2 = __fadd_rn(__fadd_rn(__fmul_rn(dx, dx), __fmul_rn(dy, dy)),
                                     __fmul_rn(dz, dz));
                float nd = fminf(dist[s], d2);
                dist[s] = nd;
                unsigned long long key =
                    ((unsigned long long)__float_as_uint(nd) << 32) | (unsigned)(~(unsigned)g);
                best = key > best ? key : best;
            }
        }
#pragma unroll
        for (int o = 32; o > 0; o >>= 1) {
            unsigned long long o2 = __shfl_xor(best, o, 64);
            best = o2 > best ? o2 : best;
        }
        if ((tid & 63) == 0) wkey[w] = best;
        __syncthreads();
        unsigned long long m0 = wkey[0] > wkey[1] ? wkey[0] : wkey[1];
        unsigned long long m1 = wkey[2] > wkey[3] ? wkey[2] : wkey[3];
        unsigned long long mm = m0 > m1 ? m0 : m1;
        far = (int)(~(unsigned)(mm & 0xFFFFFFFFu));
        __syncthreads();
    }
}

// ---------------------------------------------------------------------------
// K4: gather outputs. blocks [0,8192): features; [8192,8288): xyz.
// ---------------------------------------------------------------------------
__global__ __launch_bounds__(256) void k_gather(const float* __restrict__ xyz,
                                                const float* __restrict__ feat,
                                                const int* __restrict__ sel,
                                                float* __restrict__ out) {
    const int blk = blockIdx.x;
    if (blk < 8192) {
        int b = blk >> 10;
        int r = blk & 1023;
        int c = r >> 2;
        int t = ((r & 3) << 8) + threadIdx.x;
        int s = sel[(b << 10) + t];
        out[BB * TARGET * 3 + (((b << 8) + c) << 10) + t] =
            feat[(size_t)(((b << 8) + c) << 12) + s];
    } else {
        int e = ((blk - 8192) << 8) + threadIdx.x;  // < 24576
        int b = e / (TARGET * 3);
        int r = e % (TARGET * 3);
        int t = r / 3;
        int comp = r % 3;
        int s = sel[(b << 10) + t];
        out[e] = xyz[((size_t)(b << 12) + s) * 3 + comp];
    }
}

// ---------------------------------------------------------------------------
extern "C" void kernel_launch(void* const* d_in, const int* in_sizes, int n_in,
                              void* d_out, int out_size, void* d_ws, size_t ws_size,
                              hipStream_t stream) {
    const float* xyz  = (const float*)d_in[0];   // (B, N, 3)
    const float* feat = (const float*)d_in[1];   // (B, C, N)
    float* out = (float*)d_out;                  // xyz_out (B,1024,3) ++ feat_out (B,256,1024)

    // workspace layout (floats/ints, 4B each)
    float* curv = (float*)d_ws;                          // B*N            = 32768
    int*   sel  = (int*)(curv + BB * NN);                // B*TARGET       = 8192
    int*   ridx = (int*)(sel + BB * TARGET);             // B*RPAD         = 28672
    float* rx   = (float*)(ridx + BB * RPAD);            // B*RPAD
    float* ry   = rx + BB * RPAD;
    float* rz   = ry + BB * RPAD;

    k_curv<<<BB * (NN / 16), 1024, 0, stream>>>(xyz, curv);
    k_sort<<<BB, 1024, 0, stream>>>(curv, xyz, sel, ridx, rx, ry, rz);
    k_fps<<<BB, 256, 0, stream>>>(ridx, rx, ry, rz, sel);
    k_gather<<<8192 + (BB * TARGET * 3) / 256, 256, 0, stream>>>(xyz, feat, sel, out);
}

// Round 11
// 700.199 us; speedup vs baseline: 1.2785x; 1.2785x over previous
//
#include <hip/hip_runtime.h>
#include <hip/hip_bf16.h>

// Force separate mul/add everywhere: selection boundaries are decided at ULP
// level and must match numpy (and match across the two d2-computing passes).
#pragma clang fp contract(off)

#define BB 8
#define NN 4096
#define CC 256
#define TARGET 1024
#define NHI 614
#define NUNI 410
#define NREM 3482   // NN - NHI
#define RPAD 3584   // padded per-batch stride for rem arrays

// ---------------------------------------------------------------------------
// K1: curvature = unbiased variance of 16-NN (sqrt) distances, one wave/row.
// Round-1 proven structure (sorted-insertion top-17 + pop-merge) + threshold
// gate: T = 17th-smallest of per-lane minima (rank counting) * (1+2^-10)
// margin. All global top-17 have d2 <= T, so selection exact; margin guards
// against any residual pass1-vs-pass2 FP discrepancy.
// ---------------------------------------------------------------------------
__global__ __launch_bounds__(1024) void k_curv(const float* __restrict__ xyz,
                                               float* __restrict__ curv) {
#pragma clang fp contract(off)
    __shared__ float lx[NN], ly[NN], lz[NN];
    const int b    = blockIdx.x >> 8;           // 256 blocks per batch
    const int row0 = (blockIdx.x & 255) << 4;   // 16 rows per block
    const int tid  = threadIdx.x;

    for (int i = tid; i < NN; i += 1024) {
        const float* p = xyz + ((size_t)b * NN + i) * 3;
        lx[i] = p[0]; ly[i] = p[1]; lz[i] = p[2];
    }
    __syncthreads();

    const int lane = tid & 63;
    const int row  = row0 + (tid >> 6);
    const float px = lx[row], py = ly[row], pz = lz[row];

    // ---- pass 1: per-lane min of d2 over 64 candidates (incl. self d2=0)
    float mn = __builtin_huge_valf();
#pragma unroll 8
    for (int k = 0; k < 64; ++k) {
        const int j = lane + (k << 6);
        float dx = __fsub_rn(lx[j], px);
        float dy = __fsub_rn(ly[j], py);
        float dz = __fsub_rn(lz[j], pz);
        float d2 = __fadd_rn(__fadd_rn(__fmul_rn(dx, dx), __fmul_rn(dy, dy)),
                             __fmul_rn(dz, dz));
        mn = fminf(mn, d2);
    }

    // ---- T = 17th smallest lane-min via rank counting (total order by
    //      (value, lane)); exactly one lane has rank 16. Then safety margin.
    int rank = 0;
#pragma unroll
    for (int s = 0; s < 64; ++s) {
        float ms = __shfl(mn, s, 64);
        rank += (ms < mn || (ms == mn && s < lane)) ? 1 : 0;
    }
    float cand = (rank == 16) ? mn : __builtin_huge_valf();
#pragma unroll
    for (int o = 32; o > 0; o >>= 1) cand = fminf(cand, __shfl_xor(cand, o, 64));
    const float T = cand * 1.0009765625f;   // (1 + 2^-10) margin

    // ---- pass 2: round-1 sorted-insertion top-17, gated by d2 <= T
    unsigned long long lst[17];
#pragma unroll
    for (int s = 0; s < 17; ++s) lst[s] = ~0ULL;

    for (int k = 0; k < 64; ++k) {
        const int j = lane + (k << 6);
        float dx = __fsub_rn(lx[j], px);
        float dy = __fsub_rn(ly[j], py);
        float dz = __fsub_rn(lz[j], pz);
        float d2 = __fadd_rn(__fadd_rn(__fmul_rn(dx, dx), __fmul_rn(dy, dy)),
                             __fmul_rn(dz, dz));
        unsigned long long key =
            ((unsigned long long)__float_as_uint(d2) << 32) | (unsigned)j;
        if (d2 <= T && key < lst[16]) {
            lst[16] = key;
#pragma unroll
            for (int s = 16; s > 0; --s) {   // bubble the new element up
                if (lst[s] < lst[s - 1]) {
                    unsigned long long t = lst[s];
                    lst[s] = lst[s - 1];
                    lst[s - 1] = t;
                }
            }
        }
    }

    // ---- wave-wide pop-merge: 17 rounds of min-butterfly (round-1 verbatim)
    float dv[17];
#pragma unroll
    for (int r = 0; r < 17; ++r) {
        unsigned long long mine = lst[0];
        unsigned long long h = mine;
#pragma unroll
        for (int o = 32; o > 0; o >>= 1) {
            unsigned long long other = __shfl_xor(h, o, 64);
            h = other < h ? other : h;
        }
        if (mine == h) {          // unique owner pops (keys are unique by idx)
#pragma unroll
            for (int s = 0; s < 16; ++s) lst[s] = lst[s + 1];
            lst[16] = ~0ULL;
        }
        dv[r] = __fsqrt_rn(__uint_as_float((unsigned)(h >> 32)));
    }

    // ---- mean & unbiased variance over dv[1..16] (round-1 verbatim)
    float sum = 0.0f;
#pragma unroll
    for (int r = 1; r < 17; ++r) sum = __fadd_rn(sum, dv[r]);
    float mean = __fmul_rn(sum, 0.0625f);
    float vs = 0.0f;
#pragma unroll
    for (int r = 1; r < 17; ++r) {
        float c = __fsub_rn(dv[r], mean);
        vs = __fadd_rn(vs, __fmul_rn(c, c));
    }
    float var = __fdiv_rn(vs, 15.0f);

    if (lane == 0) curv[b * NN + row] = var;
}

// ---------------------------------------------------------------------------
// K2: per-batch bitonic sort (desc curv, asc idx) -> hi[614]; mask + prefix
//     scan -> rem indices (ascending) + gathered SoA coords.
// ---------------------------------------------------------------------------
__global__ __launch_bounds__(1024) void k_sort(const float* __restrict__ curv,
                                               const float* __restrict__ xyz,
                                               int* __restrict__ sel,
                                               int* __restrict__ ridx,
                                               float* __restrict__ rx,
                                               float* __restrict__ ry,
                                               float* __restrict__ rz) {
    __shared__ unsigned long long keys[NN];
    __shared__ unsigned int valid[NN];
    __shared__ int wsum[16];
    __shared__ int woff[16];
    const int b = blockIdx.x;
    const int tid = threadIdx.x;
    const int lane = tid & 63;
    const int w = tid >> 6;

    for (int i = tid; i < NN; i += 1024) {
        float c = curv[b * NN + i];
        keys[i] = ((unsigned long long)(~__float_as_uint(c)) << 32) | (unsigned)i;
        valid[i] = 1u;
    }
    __syncthreads();

    for (int k = 2; k <= NN; k <<= 1) {
        for (int j = k >> 1; j > 0; j >>= 1) {
            for (int i = tid; i < NN; i += 1024) {
                int ixj = i ^ j;
                if (ixj > i) {
                    unsigned long long a = keys[i], c = keys[ixj];
                    bool up = ((i & k) == 0);
                    if ((a > c) == up) { keys[i] = c; keys[ixj] = a; }
                }
            }
            __syncthreads();
        }
    }

    if (tid < NHI) {
        int hi = (int)(unsigned)(keys[tid] & 0xFFFFFFFFu);
        sel[b * TARGET + tid] = hi;
        valid[hi] = 0u;
    }
    __syncthreads();

    // block exclusive scan over 4096 validity flags, 4 per thread (index order)
    const int i0 = tid * 4;
    int v0 = (int)valid[i0], v1 = (int)valid[i0 + 1];
    int v2 = (int)valid[i0 + 2], v3 = (int)valid[i0 + 3];
    int msum = v0 + v1 + v2 + v3;
    int scan = msum;
#pragma unroll
    for (int o = 1; o < 64; o <<= 1) {
        int n = __shfl_up(scan, o, 64);
        if (lane >= o) scan += n;
    }
    if (lane == 63) wsum[w] = scan;
    __syncthreads();
    if (tid == 0) {
        int acc = 0;
        for (int q = 0; q < 16; ++q) { woff[q] = acc; acc += wsum[q]; }
    }
    __syncthreads();
    int pos = woff[w] + (scan - msum);

    const float* xb = xyz + (size_t)b * NN * 3;
    const int rb = b * RPAD;
    if (v0) { ridx[rb + pos] = i0;     rx[rb + pos] = xb[i0 * 3];       ry[rb + pos] = xb[i0 * 3 + 1];       rz[rb + pos] = xb[i0 * 3 + 2];       ++pos; }
    if (v1) { ridx[rb + pos] = i0 + 1; rx[rb + pos] = xb[(i0 + 1) * 3]; ry[rb + pos] = xb[(i0 + 1) * 3 + 1]; rz[rb + pos] = xb[(i0 + 1) * 3 + 2]; ++pos; }
    if (v2) { ridx[rb + pos] = i0 + 2; rx[rb + pos] = xb[(i0 + 2) * 3]; ry[rb + pos] = xb[(i0 + 2) * 3 + 1]; rz[rb + pos] = xb[(i0 + 2) * 3 + 2]; ++pos; }
    if (v3) { ridx[rb + pos] = i0 + 3; rx[rb + pos] = xb[(i0 + 3) * 3]; ry[rb + pos] = xb[(i0 + 3) * 3 + 1]; rz[rb + pos] = xb[(i0 + 3) * 3 + 2]; ++pos; }
}

// ---------------------------------------------------------------------------
// K3: farthest point sampling, one block (256 thr) per batch, 410 serial iters
// (round-1 known-good version)
// ---------------------------------------------------------------------------
__global__ __launch_bounds__(256) void k_fps(const int* __restrict__ ridx,
                                             const float* __restrict__ rx,
                                             const float* __restrict__ ry,
                                             const float* __restrict__ rz,
                                             int* __restrict__ sel) {
    __shared__ float sx[NREM], sy[NREM], sz[NREM];
    __shared__ int sid[NREM];
    __shared__ unsigned long long wkey[4];
    const int b = blockIdx.x, tid = threadIdx.x;
    const int w = tid >> 6;
    const int rb = b * RPAD;

    float px[14], py[14], pz[14], dist[14];
#pragma unroll
    for (int s = 0; s < 14; ++s) {
        int g = tid + 256 * s;
        bool ok = g < NREM;
        int gi = ok ? g : 0;
        float x = rx[rb + gi], y = ry[rb + gi], z = rz[rb + gi];
        px[s] = x; py[s] = y; pz[s] = z;
        dist[s] = ok ? __builtin_huge_valf() : -1.0f;
        if (ok) { sx[g] = x; sy[g] = y; sz[g] = z; sid[g] = ridx[rb + g]; }
    }
    __syncthreads();

    int far = 0;
    for (int it = 0; it < NUNI; ++it) {
        if (tid == 0) sel[b * TARGET + NHI + it] = sid[far];  // emit carry (pre-update)
        const float fx = sx[far], fy = sy[far], fz = sz[far];
        unsigned long long best = 0ULL;
#pragma unroll
        for (int s = 0; s < 14; ++s) {
            int g = tid + 256 * s;
            if (g < NREM) {
                float dx = __fsub_rn(px[s], fx);
                float dy = __fsub_rn(py[s], fy);
                float dz = __fsub_rn(pz[s], fz);
                float d2 = __fadd_rn(__fadd_rn(__fmul_rn(dx, dx), __fmul_rn(dy, dy)),
                                     __fmul_rn(dz, dz));
                float nd = fminf(dist[s], d2);
                dist[s] = nd;
                unsigned long long key =
                    ((unsigned long long)__float_as_uint(nd) << 32) | (unsigned)(~(unsigned)g);
                best = key > best ? key : best;
            }
        }
#pragma unroll
        for (int o = 32; o > 0; o >>= 1) {
            unsigned long long o2 = __shfl_xor(best, o, 64);
            best = o2 > best ? o2 : best;
        }
        if ((tid & 63) == 0) wkey[w] = best;
        __syncthreads();
        unsigned long long m0 = wkey[0] > wkey[1] ? wkey[0] : wkey[1];
        unsigned long long m1 = wkey[2] > wkey[3] ? wkey[2] : wkey[3];
        unsigned long long mm = m0 > m1 ? m0 : m1;
        far = (int)(~(unsigned)(mm & 0xFFFFFFFFu));
        __syncthreads();
    }
}

// ---------------------------------------------------------------------------
// K4: gather outputs. blocks [0,8192): features; [8192,8288): xyz.
// ---------------------------------------------------------------------------
__global__ __launch_bounds__(256) void k_gather(const float* __restrict__ xyz,
                                                const float* __restrict__ feat,
                                                const int* __restrict__ sel,
                                                float* __restrict__ out) {
    const int blk = blockIdx.x;
    if (blk < 8192) {
        int b = blk >> 10;
        int r = blk & 1023;
        int c = r >> 2;
        int t = ((r & 3) << 8) + threadIdx.x;
        int s = sel[(b << 10) + t];
        out[BB * TARGET * 3 + (((b << 8) + c) << 10) + t] =
            feat[(size_t)(((b << 8) + c) << 12) + s];
    } else {
        int e = ((blk - 8192) << 8) + threadIdx.x;  // < 24576
        int b = e / (TARGET * 3);
        int r = e % (TARGET * 3);
        int t = r / 3;
        int comp = r % 3;
        int s = sel[(b << 10) + t];
        out[e] = xyz[((size_t)(b << 12) + s) * 3 + comp];
    }
}

// ---------------------------------------------------------------------------
extern "C" void kernel_launch(void* const* d_in, const int* in_sizes, int n_in,
                              void* d_out, int out_size, void* d_ws, size_t ws_size,
                              hipStream_t stream) {
    const float* xyz  = (const float*)d_in[0];   // (B, N, 3)
    const float* feat = (const float*)d_in[1];   // (B, C, N)
    float* out = (float*)d_out;                  // xyz_out (B,1024,3) ++ feat_out (B,256,1024)

    float* curv = (float*)d_ws;                          // B*N
    int*   sel  = (int*)(curv + BB * NN);                // B*TARGET
    int*   ridx = (int*)(sel + BB * TARGET);             // B*RPAD
    float* rx   = (float*)(ridx + BB * RPAD);            // B*RPAD
    float* ry   = rx + BB * RPAD;
    float* rz   = ry + BB * RPAD;

    k_curv<<<BB * (NN / 16), 1024, 0, stream>>>(xyz, curv);
    k_sort<<<BB, 1024, 0, stream>>>(curv, xyz, sel, ridx, rx, ry, rz);
    k_fps<<<BB, 256, 0, stream>>>(ridx, rx, ry, rz, sel);
    k_gather<<<8192 + (BB * TARGET * 3) / 256, 256, 0, stream>>>(xyz, feat, sel, out);
}

// Round 13
// 689.452 us; speedup vs baseline: 1.2984x; 1.0156x over previous
//
#include <hip/hip_runtime.h>
#include <hip/hip_bf16.h>

// Force separate mul/add everywhere: selection boundaries are decided at ULP
// level and must match numpy (and match across the two d2-computing passes).
#pragma clang fp contract(off)

#define BB 8
#define NN 4096
#define CC 256
#define TARGET 1024
#define NHI 614
#define NUNI 410
#define NREM 3482   // NN - NHI
#define RPAD 3584   // padded per-batch stride for rem arrays

// ---------------------------------------------------------------------------
// K1: curvature = unbiased variance of 16-NN (sqrt) distances, one wave/row.
// (round-10 passing version, verbatim)
// ---------------------------------------------------------------------------
__global__ __launch_bounds__(1024) void k_curv(const float* __restrict__ xyz,
                                               float* __restrict__ curv) {
#pragma clang fp contract(off)
    __shared__ float lx[NN], ly[NN], lz[NN];
    const int b    = blockIdx.x >> 8;           // 256 blocks per batch
    const int row0 = (blockIdx.x & 255) << 4;   // 16 rows per block
    const int tid  = threadIdx.x;

    for (int i = tid; i < NN; i += 1024) {
        const float* p = xyz + ((size_t)b * NN + i) * 3;
        lx[i] = p[0]; ly[i] = p[1]; lz[i] = p[2];
    }
    __syncthreads();

    const int lane = tid & 63;
    const int row  = row0 + (tid >> 6);
    const float px = lx[row], py = ly[row], pz = lz[row];

    // ---- pass 1: per-lane min of d2 over 64 candidates (incl. self d2=0)
    float mn = __builtin_huge_valf();
#pragma unroll 8
    for (int k = 0; k < 64; ++k) {
        const int j = lane + (k << 6);
        float dx = __fsub_rn(lx[j], px);
        float dy = __fsub_rn(ly[j], py);
        float dz = __fsub_rn(lz[j], pz);
        float d2 = __fadd_rn(__fadd_rn(__fmul_rn(dx, dx), __fmul_rn(dy, dy)),
                             __fmul_rn(dz, dz));
        mn = fminf(mn, d2);
    }

    // ---- T = 17th smallest lane-min via rank counting + safety margin
    int rank = 0;
#pragma unroll
    for (int s = 0; s < 64; ++s) {
        float ms = __shfl(mn, s, 64);
        rank += (ms < mn || (ms == mn && s < lane)) ? 1 : 0;
    }
    float cand = (rank == 16) ? mn : __builtin_huge_valf();
#pragma unroll
    for (int o = 32; o > 0; o >>= 1) cand = fminf(cand, __shfl_xor(cand, o, 64));
    const float T = cand * 1.0009765625f;   // (1 + 2^-10) margin

    // ---- pass 2: sorted-insertion top-17, gated by d2 <= T
    unsigned long long lst[17];
#pragma unroll
    for (int s = 0; s < 17; ++s) lst[s] = ~0ULL;

    for (int k = 0; k < 64; ++k) {
        const int j = lane + (k << 6);
        float dx = __fsub_rn(lx[j], px);
        float dy = __fsub_rn(ly[j], py);
        float dz = __fsub_rn(lz[j], pz);
        float d2 = __fadd_rn(__fadd_rn(__fmul_rn(dx, dx), __fmul_rn(dy, dy)),
                             __fmul_rn(dz, dz));
        unsigned long long key =
            ((unsigned long long)__float_as_uint(d2) << 32) | (unsigned)j;
        if (d2 <= T && key < lst[16]) {
            lst[16] = key;
#pragma unroll
            for (int s = 16; s > 0; --s) {   // bubble the new element up
                if (lst[s] < lst[s - 1]) {
                    unsigned long long t = lst[s];
                    lst[s] = lst[s - 1];
                    lst[s - 1] = t;
                }
            }
        }
    }

    // ---- wave-wide pop-merge: 17 rounds of min-butterfly
    float dv[17];
#pragma unroll
    for (int r = 0; r < 17; ++r) {
        unsigned long long mine = lst[0];
        unsigned long long h = mine;
#pragma unroll
        for (int o = 32; o > 0; o >>= 1) {
            unsigned long long other = __shfl_xor(h, o, 64);
            h = other < h ? other : h;
        }
        if (mine == h) {          // unique owner pops (keys are unique by idx)
#pragma unroll
            for (int s = 0; s < 16; ++s) lst[s] = lst[s + 1];
            lst[16] = ~0ULL;
        }
        dv[r] = __fsqrt_rn(__uint_as_float((unsigned)(h >> 32)));
    }

    // ---- mean & unbiased variance over dv[1..16]
    float sum = 0.0f;
#pragma unroll
    for (int r = 1; r < 17; ++r) sum = __fadd_rn(sum, dv[r]);
    float mean = __fmul_rn(sum, 0.0625f);
    float vs = 0.0f;
#pragma unroll
    for (int r = 1; r < 17; ++r) {
        float c = __fsub_rn(dv[r], mean);
        vs = __fadd_rn(vs, __fmul_rn(c, c));
    }
    float var = __fdiv_rn(vs, 15.0f);

    if (lane == 0) curv[b * NN + row] = var;
}

// ---------------------------------------------------------------------------
// K2: per-batch bitonic sort (desc curv, asc idx) -> hi[614]; mask + prefix
//     scan -> rem indices (ascending) + gathered SoA coords.
// ---------------------------------------------------------------------------
__global__ __launch_bounds__(1024) void k_sort(const float* __restrict__ curv,
                                               const float* __restrict__ xyz,
                                               int* __restrict__ sel,
                                               int* __restrict__ ridx,
                                               float* __restrict__ rx,
                                               float* __restrict__ ry,
                                               float* __restrict__ rz) {
    __shared__ unsigned long long keys[NN];
    __shared__ unsigned int valid[NN];
    __shared__ int wsum[16];
    __shared__ int woff[16];
    const int b = blockIdx.x;
    const int tid = threadIdx.x;
    const int lane = tid & 63;
    const int w = tid >> 6;

    for (int i = tid; i < NN; i += 1024) {
        float c = curv[b * NN + i];
        keys[i] = ((unsigned long long)(~__float_as_uint(c)) << 32) | (unsigned)i;
        valid[i] = 1u;
    }
    __syncthreads();

    for (int k = 2; k <= NN; k <<= 1) {
        for (int j = k >> 1; j > 0; j >>= 1) {
            for (int i = tid; i < NN; i += 1024) {
                int ixj = i ^ j;
                if (ixj > i) {
                    unsigned long long a = keys[i], c = keys[ixj];
                    bool up = ((i & k) == 0);
                    if ((a > c) == up) { keys[i] = c; keys[ixj] = a; }
                }
            }
            __syncthreads();
        }
    }

    if (tid < NHI) {
        int hi = (int)(unsigned)(keys[tid] & 0xFFFFFFFFu);
        sel[b * TARGET + tid] = hi;
        valid[hi] = 0u;
    }
    __syncthreads();

    // block exclusive scan over 4096 validity flags, 4 per thread (index order)
    const int i0 = tid * 4;
    int v0 = (int)valid[i0], v1 = (int)valid[i0 + 1];
    int v2 = (int)valid[i0 + 2], v3 = (int)valid[i0 + 3];
    int msum = v0 + v1 + v2 + v3;
    int scan = msum;
#pragma unroll
    for (int o = 1; o < 64; o <<= 1) {
        int n = __shfl_up(scan, o, 64);
        if (lane >= o) scan += n;
    }
    if (lane == 63) wsum[w] = scan;
    __syncthreads();
    if (tid == 0) {
        int acc = 0;
        for (int q = 0; q < 16; ++q) { woff[q] = acc; acc += wsum[q]; }
    }
    __syncthreads();
    int pos = woff[w] + (scan - msum);

    const float* xb = xyz + (size_t)b * NN * 3;
    const int rb = b * RPAD;
    if (v0) { ridx[rb + pos] = i0;     rx[rb + pos] = xb[i0 * 3];       ry[rb + pos] = xb[i0 * 3 + 1];       rz[rb + pos] = xb[i0 * 3 + 2];       ++pos; }
    if (v1) { ridx[rb + pos] = i0 + 1; rx[rb + pos] = xb[(i0 + 1) * 3]; ry[rb + pos] = xb[(i0 + 1) * 3 + 1]; rz[rb + pos] = xb[(i0 + 1) * 3 + 2]; ++pos; }
    if (v2) { ridx[rb + pos] = i0 + 2; rx[rb + pos] = xb[(i0 + 2) * 3]; ry[rb + pos] = xb[(i0 + 2) * 3 + 1]; rz[rb + pos] = xb[(i0 + 2) * 3 + 2]; ++pos; }
    if (v3) { ridx[rb + pos] = i0 + 3; rx[rb + pos] = xb[(i0 + 3) * 3]; ry[rb + pos] = xb[(i0 + 3) * 3 + 1]; rz[rb + pos] = xb[(i0 + 3) * 3 + 2]; ++pos; }
}

// ---------------------------------------------------------------------------
// K3: FPS, one block (512 thr) per batch, 410 serial iters, ONE barrier/iter
// via double-buffered per-wave partials (exonerated by round-6/8 bisect:
// identical failure with and without this kernel; bug was k_curv contraction).
// Cross-iter safety: barrier B_{it+1} orders every wave's read of buffer
// (it&1) before its overwrite in iter it+2.
// ---------------------------------------------------------------------------
__global__ __launch_bounds__(512) void k_fps(const int* __restrict__ ridx,
                                             const float* __restrict__ rx,
                                             const float* __restrict__ ry,
                                             const float* __restrict__ rz,
                                             int* __restrict__ sel) {
    __shared__ float sx[NREM], sy[NREM], sz[NREM];
    __shared__ int sid[NREM];
    __shared__ unsigned long long wkey[2][8];
    const int b = blockIdx.x, tid = threadIdx.x;
    const int w = tid >> 6;
    const int rb = b * RPAD;

    float px[7], py[7], pz[7], dist[7];
#pragma unroll
    for (int s = 0; s < 7; ++s) {
        int g = tid + 512 * s;
        bool ok = g < NREM;
        int gi = ok ? g : 0;
        float x = rx[rb + gi], y = ry[rb + gi], z = rz[rb + gi];
        px[s] = x; py[s] = y; pz[s] = z;
        dist[s] = ok ? __builtin_huge_valf() : -1.0f;
        if (ok) { sx[g] = x; sy[g] = y; sz[g] = z; sid[g] = ridx[rb + g]; }
    }
    __syncthreads();

    int far = 0;
    for (int it = 0; it < NUNI; ++it) {
        // issue all 4 broadcast LDS reads together; emit is fire-and-forget
        const int   eid = sid[far];
        const float fx = sx[far], fy = sy[far], fz = sz[far];
        if (tid == 0) sel[b * TARGET + NHI + it] = eid;
        unsigned long long best = 0ULL;
#pragma unroll
        for (int s = 0; s < 7; ++s) {
            int g = tid + 512 * s;
            if (g < NREM) {
                float dx = __fsub_rn(px[s], fx);
                float dy = __fsub_rn(py[s], fy);
                float dz = __fsub_rn(pz[s], fz);
                float d2 = __fadd_rn(__fadd_rn(__fmul_rn(dx, dx), __fmul_rn(dy, dy)),
                                     __fmul_rn(dz, dz));
                float nd = fminf(dist[s], d2);
                dist[s] = nd;
                unsigned long long k2 =
                    ((unsigned long long)__float_as_uint(nd) << 32) | (unsigned)(~(unsigned)g);
                best = k2 > best ? k2 : best;
            }
        }
#pragma unroll
        for (int o = 32; o > 0; o >>= 1) {
            unsigned long long o2 = __shfl_xor(best, o, 64);
            best = o2 > best ? o2 : best;
        }
        if ((tid & 63) == 0) wkey[it & 1][w] = best;
        __syncthreads();
        unsigned long long m0 = wkey[it & 1][0], m1 = wkey[it & 1][1];
        unsigned long long m2 = wkey[it & 1][2], m3 = wkey[it & 1][3];
        unsigned long long m4 = wkey[it & 1][4], m5 = wkey[it & 1][5];
        unsigned long long m6 = wkey[it & 1][6], m7 = wkey[it & 1][7];
        m0 = m0 > m1 ? m0 : m1;  m2 = m2 > m3 ? m2 : m3;
        m4 = m4 > m5 ? m4 : m5;  m6 = m6 > m7 ? m6 : m7;
        m0 = m0 > m2 ? m0 : m2;  m4 = m4 > m6 ? m4 : m6;
        m0 = m0 > m4 ? m0 : m4;
        far = (int)(~(unsigned)(m0 & 0xFFFFFFFFu));
    }
}

// ---------------------------------------------------------------------------
// K4: gather outputs. blocks [0,8192): features; [8192,8288): xyz.
// ---------------------------------------------------------------------------
__global__ __launch_bounds__(256) void k_gather(const float* __restrict__ xyz,
                                                const float* __restrict__ feat,
                                                const int* __restrict__ sel,
                                                float* __restrict__ out) {
    const int blk = blockIdx.x;
    if (blk < 8192) {
        int b = blk >> 10;
        int r = blk & 1023;
        int c = r >> 2;
        int t = ((r & 3) << 8) + threadIdx.x;
        int s = sel[(b << 10) + t];
        out[BB * TARGET * 3 + (((b << 8) + c) << 10) + t] =
            feat[(size_t)(((b << 8) + c) << 12) + s];
    } else {
        int e = ((blk - 8192) << 8) + threadIdx.x;  // < 24576
        int b = e / (TARGET * 3);
        int r = e % (TARGET * 3);
        int t = r / 3;
        int comp = r % 3;
        int s = sel[(b << 10) + t];
        out[e] = xyz[((size_t)(b << 12) + s) * 3 + comp];
    }
}

// ---------------------------------------------------------------------------
extern "C" void kernel_launch(void* const* d_in, const int* in_sizes, int n_in,
                              void* d_out, int out_size, void* d_ws, size_t ws_size,
                              hipStream_t stream) {
    const float* xyz  = (const float*)d_in[0];   // (B, N, 3)
    const float* feat = (const float*)d_in[1];   // (B, C, N)
    float* out = (float*)d_out;                  // xyz_out (B,1024,3) ++ feat_out (B,256,1024)

    float* curv = (float*)d_ws;                          // B*N
    int*   sel  = (int*)(curv + BB * NN);                // B*TARGET
    int*   ridx = (int*)(sel + BB * TARGET);             // B*RPAD
    float* rx   = (float*)(ridx + BB * RPAD);            // B*RPAD
    float* ry   = rx + BB * RPAD;
    float* rz   = ry + BB * RPAD;

    k_curv<<<BB * (NN / 16), 1024, 0, stream>>>(xyz, curv);
    k_sort<<<BB, 1024, 0, stream>>>(curv, xyz, sel, ridx, rx, ry, rz);
    k_fps<<<BB, 512, 0, stream>>>(ridx, rx, ry, rz, sel);
    k_gather<<<8192 + (BB * TARGET * 3) / 256, 256, 0, stream>>>(xyz, feat, sel, out);
}

// Round 14
// 642.620 us; speedup vs baseline: 1.3931x; 1.0729x over previous
//
#include <hip/hip_runtime.h>
#include <hip/hip_bf16.h>

// Force separate mul/add everywhere: selection boundaries are decided at ULP
// level and must match numpy (and match across the two d2-computing passes).
#pragma clang fp contract(off)

#define BB 8
#define NN 4096
#define CC 256
#define TARGET 1024
#define NHI 614
#define NUNI 410
#define NREM 3482   // NN - NHI
#define RPAD 3584   // padded per-batch stride for rem arrays

// ---- DPP helpers: VALU-pipe cross-lane reduce (old=src keeps own value on
// lanes not written by the control; all controls are gfx9/CDNA-legal).
#define DPP_QUAD_XOR1  0xB1   // quad_perm [1,0,3,2]
#define DPP_QUAD_XOR2  0x4E   // quad_perm [2,3,0,1]
#define DPP_HALF_MIRR  0x141  // row_half_mirror (i^7 within 8)
#define DPP_ROW_MIRR   0x140  // row_mirror (i^15 within 16)
#define DPP_BCAST15    0x142  // lane15 -> lanes 16-31 (and 47 -> 48-63)
#define DPP_BCAST31    0x143  // lane31 -> lanes 32-63

template <int C>
__device__ __forceinline__ float dpp_max_f32(float v) {
    int t = __builtin_amdgcn_update_dpp(__float_as_int(v), __float_as_int(v),
                                        C, 0xF, 0xF, false);
    return fmaxf(v, __int_as_float(t));
}
template <int C>
__device__ __forceinline__ unsigned dpp_min_u32(unsigned v) {
    unsigned t = (unsigned)__builtin_amdgcn_update_dpp((int)v, (int)v,
                                                       C, 0xF, 0xF, false);
    return v < t ? v : t;
}

// ---------------------------------------------------------------------------
// K1: curvature = unbiased variance of 16-NN (sqrt) distances, one wave/row.
// (round-10 passing version, verbatim)
// ---------------------------------------------------------------------------
__global__ __launch_bounds__(1024) void k_curv(const float* __restrict__ xyz,
                                               float* __restrict__ curv) {
#pragma clang fp contract(off)
    __shared__ float lx[NN], ly[NN], lz[NN];
    const int b    = blockIdx.x >> 8;           // 256 blocks per batch
    const int row0 = (blockIdx.x & 255) << 4;   // 16 rows per block
    const int tid  = threadIdx.x;

    for (int i = tid; i < NN; i += 1024) {
        const float* p = xyz + ((size_t)b * NN + i) * 3;
        lx[i] = p[0]; ly[i] = p[1]; lz[i] = p[2];
    }
    __syncthreads();

    const int lane = tid & 63;
    const int row  = row0 + (tid >> 6);
    const float px = lx[row], py = ly[row], pz = lz[row];

    // ---- pass 1: per-lane min of d2 over 64 candidates (incl. self d2=0)
    float mn = __builtin_huge_valf();
#pragma unroll 8
    for (int k = 0; k < 64; ++k) {
        const int j = lane + (k << 6);
        float dx = __fsub_rn(lx[j], px);
        float dy = __fsub_rn(ly[j], py);
        float dz = __fsub_rn(lz[j], pz);
        float d2 = __fadd_rn(__fadd_rn(__fmul_rn(dx, dx), __fmul_rn(dy, dy)),
                             __fmul_rn(dz, dz));
        mn = fminf(mn, d2);
    }

    // ---- T = 17th smallest lane-min via rank counting + safety margin
    int rank = 0;
#pragma unroll
    for (int s = 0; s < 64; ++s) {
        float ms = __shfl(mn, s, 64);
        rank += (ms < mn || (ms == mn && s < lane)) ? 1 : 0;
    }
    float cand = (rank == 16) ? mn : __builtin_huge_valf();
#pragma unroll
    for (int o = 32; o > 0; o >>= 1) cand = fminf(cand, __shfl_xor(cand, o, 64));
    const float T = cand * 1.0009765625f;   // (1 + 2^-10) margin

    // ---- pass 2: sorted-insertion top-17, gated by d2 <= T
    unsigned long long lst[17];
#pragma unroll
    for (int s = 0; s < 17; ++s) lst[s] = ~0ULL;

    for (int k = 0; k < 64; ++k) {
        const int j = lane + (k << 6);
        float dx = __fsub_rn(lx[j], px);
        float dy = __fsub_rn(ly[j], py);
        float dz = __fsub_rn(lz[j], pz);
        float d2 = __fadd_rn(__fadd_rn(__fmul_rn(dx, dx), __fmul_rn(dy, dy)),
                             __fmul_rn(dz, dz));
        unsigned long long key =
            ((unsigned long long)__float_as_uint(d2) << 32) | (unsigned)j;
        if (d2 <= T && key < lst[16]) {
            lst[16] = key;
#pragma unroll
            for (int s = 16; s > 0; --s) {   // bubble the new element up
                if (lst[s] < lst[s - 1]) {
                    unsigned long long t = lst[s];
                    lst[s] = lst[s - 1];
                    lst[s - 1] = t;
                }
            }
        }
    }

    // ---- wave-wide pop-merge: 17 rounds of min-butterfly
    float dv[17];
#pragma unroll
    for (int r = 0; r < 17; ++r) {
        unsigned long long mine = lst[0];
        unsigned long long h = mine;
#pragma unroll
        for (int o = 32; o > 0; o >>= 1) {
            unsigned long long other = __shfl_xor(h, o, 64);
            h = other < h ? other : h;
        }
        if (mine == h) {          // unique owner pops (keys are unique by idx)
#pragma unroll
            for (int s = 0; s < 16; ++s) lst[s] = lst[s + 1];
            lst[16] = ~0ULL;
        }
        dv[r] = __fsqrt_rn(__uint_as_float((unsigned)(h >> 32)));
    }

    // ---- mean & unbiased variance over dv[1..16]
    float sum = 0.0f;
#pragma unroll
    for (int r = 1; r < 17; ++r) sum = __fadd_rn(sum, dv[r]);
    float mean = __fmul_rn(sum, 0.0625f);
    float vs = 0.0f;
#pragma unroll
    for (int r = 1; r < 17; ++r) {
        float c = __fsub_rn(dv[r], mean);
        vs = __fadd_rn(vs, __fmul_rn(c, c));
    }
    float var = __fdiv_rn(vs, 15.0f);

    if (lane == 0) curv[b * NN + row] = var;
}

// ---------------------------------------------------------------------------
// K2: per-batch bitonic sort (desc curv, asc idx) -> hi[614]; mask + prefix
//     scan -> rem indices (ascending) + gathered SoA coords.
// ---------------------------------------------------------------------------
__global__ __launch_bounds__(1024) void k_sort(const float* __restrict__ curv,
                                               const float* __restrict__ xyz,
                                               int* __restrict__ sel,
                                               int* __restrict__ ridx,
                                               float* __restrict__ rx,
                                               float* __restrict__ ry,
                                               float* __restrict__ rz) {
    __shared__ unsigned long long keys[NN];
    __shared__ unsigned int valid[NN];
    __shared__ int wsum[16];
    __shared__ int woff[16];
    const int b = blockIdx.x;
    const int tid = threadIdx.x;
    const int lane = tid & 63;
    const int w = tid >> 6;

    for (int i = tid; i < NN; i += 1024) {
        float c = curv[b * NN + i];
        keys[i] = ((unsigned long long)(~__float_as_uint(c)) << 32) | (unsigned)i;
        valid[i] = 1u;
    }
    __syncthreads();

    for (int k = 2; k <= NN; k <<= 1) {
        for (int j = k >> 1; j > 0; j >>= 1) {
            for (int i = tid; i < NN; i += 1024) {
                int ixj = i ^ j;
                if (ixj > i) {
                    unsigned long long a = keys[i], c = keys[ixj];
                    bool up = ((i & k) == 0);
                    if ((a > c) == up) { keys[i] = c; keys[ixj] = a; }
                }
            }
            __syncthreads();
        }
    }

    if (tid < NHI) {
        int hi = (int)(unsigned)(keys[tid] & 0xFFFFFFFFu);
        sel[b * TARGET + tid] = hi;
        valid[hi] = 0u;
    }
    __syncthreads();

    // block exclusive scan over 4096 validity flags, 4 per thread (index order)
    const int i0 = tid * 4;
    int v0 = (int)valid[i0], v1 = (int)valid[i0 + 1];
    int v2 = (int)valid[i0 + 2], v3 = (int)valid[i0 + 3];
    int msum = v0 + v1 + v2 + v3;
    int scan = msum;
#pragma unroll
    for (int o = 1; o < 64; o <<= 1) {
        int n = __shfl_up(scan, o, 64);
        if (lane >= o) scan += n;
    }
    if (lane == 63) wsum[w] = scan;
    __syncthreads();
    if (tid == 0) {
        int acc = 0;
        for (int q = 0; q < 16; ++q) { woff[q] = acc; acc += wsum[q]; }
    }
    __syncthreads();
    int pos = woff[w] + (scan - msum);

    const float* xb = xyz + (size_t)b * NN * 3;
    const int rb = b * RPAD;
    if (v0) { ridx[rb + pos] = i0;     rx[rb + pos] = xb[i0 * 3];       ry[rb + pos] = xb[i0 * 3 + 1];       rz[rb + pos] = xb[i0 * 3 + 2];       ++pos; }
    if (v1) { ridx[rb + pos] = i0 + 1; rx[rb + pos] = xb[(i0 + 1) * 3]; ry[rb + pos] = xb[(i0 + 1) * 3 + 1]; rz[rb + pos] = xb[(i0 + 1) * 3 + 2]; ++pos; }
    if (v2) { ridx[rb + pos] = i0 + 2; rx[rb + pos] = xb[(i0 + 2) * 3]; ry[rb + pos] = xb[(i0 + 2) * 3 + 1]; rz[rb + pos] = xb[(i0 + 2) * 3 + 2]; ++pos; }
    if (v3) { ridx[rb + pos] = i0 + 3; rx[rb + pos] = xb[(i0 + 3) * 3]; ry[rb + pos] = xb[(i0 + 3) * 3 + 1]; rz[rb + pos] = xb[(i0 + 3) * 3 + 2]; ++pos; }
}

// ---------------------------------------------------------------------------
// K3: FPS, one block (512 thr) per batch, 410 serial iters, ONE barrier/iter.
// Intra-wave argmax via DPP (VALU pipe) instead of ds_bpermute butterfly:
// 6-stage f32 max chain -> readlane(63) -> M; tie-break = 6-stage u32 min
// chain over candidate indices (first-max semantics = jnp.argmax). Cross-wave
// combine unchanged: packed (bits(M)<<32)|~idx u64 max tree, double-buffered.
// ---------------------------------------------------------------------------
__global__ __launch_bounds__(512) void k_fps(const int* __restrict__ ridx,
                                             const float* __restrict__ rx,
                                             const float* __restrict__ ry,
                                             const float* __restrict__ rz,
                                             int* __restrict__ sel) {
    __shared__ float sx[NREM], sy[NREM], sz[NREM];
    __shared__ int sid[NREM];
    __shared__ unsigned long long wkey[2][8];
    const int b = blockIdx.x, tid = threadIdx.x;
    const int w = tid >> 6;
    const int rb = b * RPAD;

    float px[7], py[7], pz[7], dist[7];
#pragma unroll
    for (int s = 0; s < 7; ++s) {
        int g = tid + 512 * s;
        bool ok = g < NREM;
        int gi = ok ? g : 0;
        float x = rx[rb + gi], y = ry[rb + gi], z = rz[rb + gi];
        px[s] = x; py[s] = y; pz[s] = z;
        dist[s] = ok ? __builtin_huge_valf() : -1.0f;
        if (ok) { sx[g] = x; sy[g] = y; sz[g] = z; sid[g] = ridx[rb + g]; }
    }
    __syncthreads();

    int far = 0;
    for (int it = 0; it < NUNI; ++it) {
        // issue all 4 broadcast LDS reads together; emit is fire-and-forget
        const int   eid = sid[far];
        const float fx = sx[far], fy = sy[far], fz = sz[far];
        if (tid == 0) sel[b * TARGET + NHI + it] = eid;

        // per-lane best (first-max: strict > over ascending g keeps lowest g)
        float    bv = -1.0f;
        unsigned bg = 0xFFFFFFFFu;
#pragma unroll
        for (int s = 0; s < 7; ++s) {
            int g = tid + 512 * s;
            if (g < NREM) {
                float dx = __fsub_rn(px[s], fx);
                float dy = __fsub_rn(py[s], fy);
                float dz = __fsub_rn(pz[s], fz);
                float d2 = __fadd_rn(__fadd_rn(__fmul_rn(dx, dx), __fmul_rn(dy, dy)),
                                     __fmul_rn(dz, dz));
                float nd = fminf(dist[s], d2);
                dist[s] = nd;
                if (nd > bv) { bv = nd; bg = (unsigned)g; }
            }
        }

        // wave max value via DPP chain (VALU), then broadcast via readlane
        float m = bv;
        m = dpp_max_f32<DPP_QUAD_XOR1>(m);
        m = dpp_max_f32<DPP_QUAD_XOR2>(m);
        m = dpp_max_f32<DPP_HALF_MIRR>(m);
        m = dpp_max_f32<DPP_ROW_MIRR>(m);
        m = dpp_max_f32<DPP_BCAST15>(m);
        m = dpp_max_f32<DPP_BCAST31>(m);
        const float M =
            __int_as_float(__builtin_amdgcn_readlane(__float_as_int(m), 63));

        // lowest index achieving M, via DPP min chain
        unsigned ci = (bv == M) ? bg : 0xFFFFFFFFu;
        ci = dpp_min_u32<DPP_QUAD_XOR1>(ci);
        ci = dpp_min_u32<DPP_QUAD_XOR2>(ci);
        ci = dpp_min_u32<DPP_HALF_MIRR>(ci);
        ci = dpp_min_u32<DPP_ROW_MIRR>(ci);
        ci = dpp_min_u32<DPP_BCAST15>(ci);
        ci = dpp_min_u32<DPP_BCAST31>(ci);
        const unsigned gi = (unsigned)__builtin_amdgcn_readlane((int)ci, 63);

        unsigned long long best =
            ((unsigned long long)__float_as_uint(M) << 32) | (unsigned)(~gi);

        if ((tid & 63) == 0) wkey[it & 1][w] = best;
        __syncthreads();
        unsigned long long m0 = wkey[it & 1][0], m1 = wkey[it & 1][1];
        unsigned long long m2 = wkey[it & 1][2], m3 = wkey[it & 1][3];
        unsigned long long m4 = wkey[it & 1][4], m5 = wkey[it & 1][5];
        unsigned long long m6 = wkey[it & 1][6], m7 = wkey[it & 1][7];
        m0 = m0 > m1 ? m0 : m1;  m2 = m2 > m3 ? m2 : m3;
        m4 = m4 > m5 ? m4 : m5;  m6 = m6 > m7 ? m6 : m7;
        m0 = m0 > m2 ? m0 : m2;  m4 = m4 > m6 ? m4 : m6;
        m0 = m0 > m4 ? m0 : m4;
        far = (int)(~(unsigned)(m0 & 0xFFFFFFFFu));
    }
}

// ---------------------------------------------------------------------------
// K4: gather outputs. blocks [0,8192): features; [8192,8288): xyz.
// ---------------------------------------------------------------------------
__global__ __launch_bounds__(256) void k_gather(const float* __restrict__ xyz,
                                                const float* __restrict__ feat,
                                                const int* __restrict__ sel,
                                                float* __restrict__ out) {
    const int blk = blockIdx.x;
    if (blk < 8192) {
        int b = blk >> 10;
        int r = blk & 1023;
        int c = r >> 2;
        int t = ((r & 3) << 8) + threadIdx.x;
        int s = sel[(b << 10) + t];
        out[BB * TARGET * 3 + (((b << 8) + c) << 10) + t] =
            feat[(size_t)(((b << 8) + c) << 12) + s];
    } else {
        int e = ((blk - 8192) << 8) + threadIdx.x;  // < 24576
        int b = e / (TARGET * 3);
        int r = e % (TARGET * 3);
        int t = r / 3;
        int comp = r % 3;
        int s = sel[(b << 10) + t];
        out[e] = xyz[((size_t)(b << 12) + s) * 3 + comp];
    }
}

// ---------------------------------------------------------------------------
extern "C" void kernel_launch(void* const* d_in, const int* in_sizes, int n_in,
                              void* d_out, int out_size, void* d_ws, size_t ws_size,
                              hipStream_t stream) {
    const float* xyz  = (const float*)d_in[0];   // (B, N, 3)
    const float* feat = (const float*)d_in[1];   // (B, C, N)
    float* out = (float*)d_out;                  // xyz_out (B,1024,3) ++ feat_out (B,256,1024)

    float* curv = (float*)d_ws;                          // B*N
    int*   sel  = (int*)(curv + BB * NN);                // B*TARGET
    int*   ridx = (int*)(sel + BB * TARGET);             // B*RPAD
    float* rx   = (float*)(ridx + BB * RPAD);            // B*RPAD
    float* ry   = rx + BB * RPAD;
    float* rz   = ry + BB * RPAD;

    k_curv<<<BB * (NN / 16), 1024, 0, stream>>>(xyz, curv);
    k_sort<<<BB, 1024, 0, stream>>>(curv, xyz, sel, ridx, rx, ry, rz);
    k_fps<<<BB, 512, 0, stream>>>(ridx, rx, ry, rz, sel);
    k_gather<<<8192 + (BB * TARGET * 3) / 256, 256, 0, stream>>>(xyz, feat, sel, out);
}